// Round 5
// baseline (1139.841 us; speedup 1.0000x reference)
//
#include <hip/hip_runtime.h>
#include <math.h>

// LSTM: B=512, T=1000, I=64, H=50, gates 4H=200 (torch order i,f,g,o).
//
// ROUND-5 STRUCTURE: one block = 256 threads serving TWO batch rows IN THE
// SAME LANES (weights are row-independent -> shared; only c/xg state doubles).
// Grid = B/2 = 256 blocks = 1 block/CU. 4 waves/CU (occupancy is intentionally
// low: the two rows' independent dependency chains inside each lane provide
// the latency hiding that lockstepped waves cannot).
//   tid < 200 : worker. lane -> (u=tid>>2, g=tid&3), gate k=g*50+u. Holds
//       W_hh row k (25 f32x2) + W_ih row k (32 f32x2) ONCE, serves rows
//       {2b, 2b+1}. Per step, per row: gates = xg_reg + h . whh (xg is a
//       register double-buffer produced by this lane 2 steps ago), activation
//       via per-lane consts, directed quad_perm DPP exchange, c update, lane
//       g==0 writes h; then produces xg for s+2 from the x LDS ring.
//   tid >= 224 : loader (32 lanes). DEPTH-4 global prefetch (4 in-flight
//       f32x2 regs per row; load x[s+7] at step s, LDS-write x[s+3]) across
//       raw lgkmcnt-only barriers -- ~4 steps of flight >> HBM latency even
//       at the shorter step time.
// ONE s_barrier per step (syncs only 4 waves).

#define HSZ 50
#define ISZ 64
#define TSZ 1000

typedef float f32x2 __attribute__((ext_vector_type(2)));

// quad_perm DPP helpers
__device__ __forceinline__ float dpp_xor1(float v) {  // [1,0,3,2]
    return __int_as_float(__builtin_amdgcn_update_dpp(
        0, __float_as_int(v), 0xB1, 0xF, 0xF, true));
}
__device__ __forceinline__ float dpp_xor2(float v) {  // [2,3,0,1]
    return __int_as_float(__builtin_amdgcn_update_dpp(
        0, __float_as_int(v), 0x4E, 0xF, 0xF, true));
}
__device__ __forceinline__ float dpp_rev(float v) {   // [3,2,1,0]
    return __int_as_float(__builtin_amdgcn_update_dpp(
        0, __float_as_int(v), 0x1B, 0xF, 0xF, true));
}

// Per-row consume (step s) + produce (xg for s+2). R: row 0/1 (compile-time),
// C: that row's c register, XG: that row's xg register for parity s&1.
#define ROW_STEP(R, C, XG, OFF, t)                                             \
  {                                                                            \
    f32x2 accA; accA.x = XG; accA.y = 0.0f;                                    \
    f32x2 accB; accB.x = 0.0f; accB.y = 0.0f;                                  \
    const float4* h4 = (const float4*)(&hbuf[R][(OFF) & 1][0]);                \
    _Pragma("unroll")                                                          \
    for (int j = 0; j < 12; ++j) {                                             \
      float4 v = h4[j];                                                        \
      f32x2 lo; lo.x = v.x; lo.y = v.y;                                        \
      f32x2 hi; hi.x = v.z; hi.y = v.w;                                        \
      accA += lo * whh[2 * j];                                                 \
      accB += hi * whh[2 * j + 1];                                             \
    }                                                                          \
    { f32x2 tl = *(const f32x2*)(&hbuf[R][(OFF) & 1][48]);                     \
      accA += tl * whh[24]; }                                                  \
    float acc = (accA.x + accB.x) + (accA.y + accB.y);                         \
    float e  = __expf(-(acc * gmul));                                          \
    float sg = __builtin_amdgcn_rcpf(1.0f + e);                                \
    float a  = __builtin_fmaf(sg, gma, gmb);      /* sigmoid or tanh */        \
    float fg = dpp_xor1(a);                                                    \
    float gg = dpp_xor2(a);                                                    \
    float og = dpp_rev(a);                                                     \
    C = __builtin_fmaf(fg, C, a * gg);            /* a == i on g==0 lane */    \
    float ep = __expf(2.0f * C);                                               \
    float rr = __builtin_amdgcn_rcpf(1.0f + ep);                               \
    float hv = __builtin_fmaf(-2.0f * og, rr, og); /* og * tanh(c) */          \
    if ((tid & 3) == 0) hbuf[R][((OFF) + 1) & 1][u] = hv;                      \
    if ((t) + (OFF) + 2 < TSZ) {                                               \
      f32x2 pA; pA.x = bias; pA.y = 0.0f;                                      \
      f32x2 pB; pB.x = 0.0f; pB.y = 0.0f;                                      \
      const float4* x4 = (const float4*)(&xbuf[R][((OFF) + 2) & 3][0]);        \
      _Pragma("unroll")                                                        \
      for (int i = 0; i < 16; ++i) {                                           \
        float4 v = x4[i];                                                      \
        f32x2 lo; lo.x = v.x; lo.y = v.y;                                      \
        f32x2 hi; hi.x = v.z; hi.y = v.w;                                      \
        pA += lo * wih[2 * i];                                                 \
        pB += hi * wih[2 * i + 1];                                             \
      }                                                                        \
      XG = (pA.x + pB.x) + (pA.y + pB.y);                                      \
    }                                                                          \
  }

// One step, s = t+OFF, OFF compile-time in {0,1,2,3}; t%4==0.
#define LSTM_STEP(t, OFF, XR0, XR1, XG0, XG1)                                  \
  {                                                                            \
    if (tid < 200) {                                                           \
      ROW_STEP(0, c0, XG0, OFF, t)                                             \
      ROW_STEP(1, c1, XG1, OFF, t)                                             \
    } else if (tid >= 224) {                                                   \
      if ((t) + (OFF) + 3 < TSZ) {                                             \
        *(f32x2*)(&xbuf[0][((OFF) + 3) & 3][2 * ll]) = XR0;                    \
        *(f32x2*)(&xbuf[1][((OFF) + 3) & 3][2 * ll]) = XR1;                    \
      }                                                                        \
      if ((t) + (OFF) + 7 < TSZ) {                                             \
        XR0 = *(const f32x2*)(xrow0 + (size_t)((t) + (OFF) + 7) * ISZ + 2*ll); \
        XR1 = *(const f32x2*)(xrow1 + (size_t)((t) + (OFF) + 7) * ISZ + 2*ll); \
      }                                                                        \
    }                                                                          \
    /* drain LDS only; loader's global loads stay in flight */                 \
    asm volatile("s_waitcnt lgkmcnt(0)" ::: "memory");                         \
    __builtin_amdgcn_s_barrier();                                              \
    __builtin_amdgcn_sched_barrier(0);                                         \
  }

__global__ __launch_bounds__(256, 1) void lstm_fused(
    const float* __restrict__ x,      // [B, T, I]
    const float* __restrict__ W_ih,   // [4H, I]
    const float* __restrict__ W_hh,   // [4H, H]
    const float* __restrict__ b_ih,   // [4H]
    const float* __restrict__ b_hh,   // [4H]
    const float* __restrict__ W_out,  // [2, H]
    const float* __restrict__ b_out,  // [2]
    float* __restrict__ out)          // [B, 2]
{
    const int bb  = blockIdx.x;
    const int tid = threadIdx.x;

    __shared__ __align__(16) float xbuf[2][4][ISZ];   // x ring per row (2 KiB)
    __shared__ __align__(16) float hbuf[2][2][56];    // h ping-pong per row

    // worker coords (valid tid<200)
    const int g = tid & 3;            // 0=i 1=f 2=g 3=o
    const int u = tid >> 2;           // unit
    const int k = g * HSZ + u;        // gate row in [0,200)
    const float gmul = (g == 2) ? 2.0f : 1.0f;
    const float gma  = (g == 2) ? 2.0f : 1.0f;
    const float gmb  = (g == 2) ? -1.0f : 0.0f;

    const int ll = tid - 224;         // loader lane 0..31 (tid>=224)

    const float* xrow0 = x + (size_t)(2 * bb)     * (TSZ * ISZ);
    const float* xrow1 = x + (size_t)(2 * bb + 1) * (TSZ * ISZ);

    // shared-across-rows weights (loaded once per lane)
    f32x2 whh[25];
    f32x2 wih[32];
    float bias = 0.0f;
    float c0 = 0.0f, c1 = 0.0f;            // cell state per row
    float xgE0 = 0.0f, xgE1 = 0.0f;        // xg regs, even steps
    float xgO0 = 0.0f, xgO1 = 0.0f;        // xg regs, odd steps
    // loader in-flight regs: 4-deep per row
    f32x2 xrA0{}, xrA1{}, xrA2{}, xrA3{};  // row 0
    f32x2 xrB0{}, xrB1{}, xrB2{}, xrB3{};  // row 1

    if (tid < 200) {
        const float* wh = W_hh + k * HSZ;
        #pragma unroll
        for (int j = 0; j < 25; ++j) whh[j] = *(const f32x2*)(wh + 2 * j);
        const float* wi = W_ih + k * ISZ;
        #pragma unroll
        for (int i = 0; i < 32; ++i) wih[i] = *(const f32x2*)(wi + 2 * i);
        bias = b_ih[k] + b_hh[k];
    } else if (ll >= 0) {
        // stage x[0..2] for both rows; preload regs with x[3..6]
        #pragma unroll
        for (int n = 0; n < 3; ++n) {
            *(f32x2*)(&xbuf[0][n][2 * ll]) =
                *(const f32x2*)(xrow0 + (size_t)n * ISZ + 2 * ll);
            *(f32x2*)(&xbuf[1][n][2 * ll]) =
                *(const f32x2*)(xrow1 + (size_t)n * ISZ + 2 * ll);
        }
        xrA0 = *(const f32x2*)(xrow0 + 3 * (size_t)ISZ + 2 * ll);
        xrA1 = *(const f32x2*)(xrow0 + 4 * (size_t)ISZ + 2 * ll);
        xrA2 = *(const f32x2*)(xrow0 + 5 * (size_t)ISZ + 2 * ll);
        xrA3 = *(const f32x2*)(xrow0 + 6 * (size_t)ISZ + 2 * ll);
        xrB0 = *(const f32x2*)(xrow1 + 3 * (size_t)ISZ + 2 * ll);
        xrB1 = *(const f32x2*)(xrow1 + 4 * (size_t)ISZ + 2 * ll);
        xrB2 = *(const f32x2*)(xrow1 + 5 * (size_t)ISZ + 2 * ll);
        xrB3 = *(const f32x2*)(xrow1 + 6 * (size_t)ISZ + 2 * ll);
    }
    if (tid < 56) {
        hbuf[0][0][tid] = 0.0f; hbuf[0][1][tid] = 0.0f;
        hbuf[1][0][tid] = 0.0f; hbuf[1][1][tid] = 0.0f;
    }
    __syncthreads();

    // xg prologue (registers only): parity-even from x[0], parity-odd from x[1]
    if (tid < 200) {
        #pragma unroll
        for (int R = 0; R < 2; ++R) {
            #pragma unroll
            for (int n = 0; n < 2; ++n) {
                f32x2 pA; pA.x = bias; pA.y = 0.0f;
                f32x2 pB; pB.x = 0.0f; pB.y = 0.0f;
                const float4* x4 = (const float4*)(&xbuf[R][n][0]);
                #pragma unroll
                for (int i = 0; i < 16; ++i) {
                    float4 v = x4[i];
                    f32x2 lo; lo.x = v.x; lo.y = v.y;
                    f32x2 hi; hi.x = v.z; hi.y = v.w;
                    pA += lo * wih[2 * i];
                    pB += hi * wih[2 * i + 1];
                }
                float r = (pA.x + pB.x) + (pA.y + pB.y);
                if (R == 0) { if (n == 0) xgE0 = r; else xgO0 = r; }
                else        { if (n == 0) xgE1 = r; else xgO1 = r; }
            }
        }
    }

    for (int t = 0; t < TSZ; t += 4) {
        LSTM_STEP(t, 0, xrA0, xrB0, xgE0, xgE1)
        LSTM_STEP(t, 1, xrA1, xrB1, xgO0, xgO1)
        LSTM_STEP(t, 2, xrA2, xrB2, xgE0, xgE1)
        LSTM_STEP(t, 3, xrA3, xrB3, xgO0, xgO1)
    }
    // last step (s=999) wrote h_final into hbuf[R][0]; its lgkmcnt(0) +
    // s_barrier makes it visible.

    if (tid < 4) {
        const int R = tid >> 1, o = tid & 1;
        float acc = b_out[o];
        const float* wo = W_out + o * HSZ;
        #pragma unroll
        for (int j = 0; j < HSZ; ++j) acc += hbuf[R][0][j] * wo[j];
        out[(2 * bb + R) * 2 + o] = acc;
    }
}

extern "C" void kernel_launch(void* const* d_in, const int* in_sizes, int n_in,
                              void* d_out, int out_size, void* d_ws, size_t ws_size,
                              hipStream_t stream) {
    const float* x     = (const float*)d_in[0];
    const float* W_ih  = (const float*)d_in[1];
    const float* W_hh  = (const float*)d_in[2];
    const float* b_ih  = (const float*)d_in[3];
    const float* b_hh  = (const float*)d_in[4];
    const float* W_out = (const float*)d_in[5];
    const float* b_out = (const float*)d_in[6];
    float* out = (float*)d_out;

    const int B = in_sizes[0] / (TSZ * ISZ);   // 512
    hipLaunchKernelGGL(lstm_fused, dim3(B / 2), dim3(256), 0, stream,
                       x, W_ih, W_hh, b_ih, b_hh, W_out, b_out, out);
}

// Round 6
// 759.412 us; speedup vs baseline: 1.5010x; 1.5010x over previous
//
#include <hip/hip_runtime.h>
#include <math.h>

// LSTM: B=512, T=1000, I=64, H=50, gates 4H=200 (torch order i,f,g,o).
//
// ROUND-6 STRUCTURE: R4's per-row machinery, but one block = ONE batch row,
// 256 threads, grid = B = 512 -> TWO INDEPENDENT BLOCKS PER CU.
// R4 (694us) ran the same 8 waves/CU under a single shared barrier: all waves
// in the same phase, so the ~950cyc/step of ds-latency + exp-chain + drain
// stall was synchronized dead time (VALUBusy 43%). R5 proved within-lane ILP
// cannot fill it (in-order waves, 1/SIMD -> 2560cyc step). R6 splits the two
// rows into separate blocks with SEPARATE barriers: blocks drift anti-phase,
// and each block's stall window is covered by the other block's issue.
//   tid < 200 : worker. lane -> (u=tid>>2, g=tid&3), gate k=g*50+u. Holds
//       W_hh row k (25 f32x2) + W_ih row k (32 f32x2) in regs. Per step:
//       gates = xg_reg + h . whh (xg = register double-buffer produced by
//       this lane 2 steps ago), activation via per-lane consts, directed
//       quad_perm DPP exchange, c update, lane g==0 writes h to LDS; then
//       produces xg for s+2 from the x LDS ring.
//   tid >= 224 : loader (32 lanes). Depth-4 global prefetch (4 in-flight
//       f32x2; at step s: LDS-write x[s+3], issue load x[s+7]) across raw
//       lgkmcnt-only barriers.
// ONE s_barrier per step (syncs only this block's 4 waves).

#define HSZ 50
#define ISZ 64
#define TSZ 1000

typedef float f32x2 __attribute__((ext_vector_type(2)));

// quad_perm DPP helpers
__device__ __forceinline__ float dpp_xor1(float v) {  // [1,0,3,2]
    return __int_as_float(__builtin_amdgcn_update_dpp(
        0, __float_as_int(v), 0xB1, 0xF, 0xF, true));
}
__device__ __forceinline__ float dpp_xor2(float v) {  // [2,3,0,1]
    return __int_as_float(__builtin_amdgcn_update_dpp(
        0, __float_as_int(v), 0x4E, 0xF, 0xF, true));
}
__device__ __forceinline__ float dpp_rev(float v) {   // [3,2,1,0]
    return __int_as_float(__builtin_amdgcn_update_dpp(
        0, __float_as_int(v), 0x1B, 0xF, 0xF, true));
}

// One step, s = t+OFF, OFF compile-time in {0,1,2,3}; t%4==0.
// XR: loader's in-flight f32x2; XG: this lane's xg register for parity s&1.
#define LSTM_STEP(t, OFF, XR, XG)                                              \
  {                                                                            \
    if (tid < 200) {                                                           \
      /* ---- consume: gates for step s ---- */                                \
      f32x2 accA; accA.x = XG; accA.y = 0.0f;                                  \
      f32x2 accB; accB.x = 0.0f; accB.y = 0.0f;                                \
      const float4* h4 = (const float4*)(&hbuf[(OFF) & 1][0]);                 \
      _Pragma("unroll")                                                        \
      for (int j = 0; j < 12; ++j) {                                           \
        float4 v = h4[j];                                                      \
        f32x2 lo; lo.x = v.x; lo.y = v.y;                                      \
        f32x2 hi; hi.x = v.z; hi.y = v.w;                                      \
        accA += lo * whh[2 * j];                                               \
        accB += hi * whh[2 * j + 1];                                           \
      }                                                                        \
      { f32x2 tl = *(const f32x2*)(&hbuf[(OFF) & 1][48]);                      \
        accA += tl * whh[24]; }                                                \
      float acc = (accA.x + accB.x) + (accA.y + accB.y);                       \
      float e  = __expf(-(acc * gmul));                                        \
      float sg = __builtin_amdgcn_rcpf(1.0f + e);                              \
      float a  = __builtin_fmaf(sg, gma, gmb);      /* sigmoid or tanh */      \
      float fg = dpp_xor1(a);                                                  \
      float gg = dpp_xor2(a);                                                  \
      float og = dpp_rev(a);                                                   \
      c_reg = __builtin_fmaf(fg, c_reg, a * gg);    /* a == i on g==0 lane */  \
      float ep = __expf(2.0f * c_reg);                                         \
      float rr = __builtin_amdgcn_rcpf(1.0f + ep);                             \
      float hv = __builtin_fmaf(-2.0f * og, rr, og); /* og * tanh(c) */        \
      if ((tid & 3) == 0) hbuf[((OFF) + 1) & 1][u] = hv;                       \
      /* ---- produce: xg for step s+2 (x staged >=1 barrier ago) ---- */      \
      if ((t) + (OFF) + 2 < TSZ) {                                             \
        f32x2 pA; pA.x = bias; pA.y = 0.0f;                                    \
        f32x2 pB; pB.x = 0.0f; pB.y = 0.0f;                                    \
        const float4* x4 = (const float4*)(&xbuf[((OFF) + 2) & 3][0]);         \
        _Pragma("unroll")                                                      \
        for (int i = 0; i < 16; ++i) {                                         \
          float4 v = x4[i];                                                    \
          f32x2 lo; lo.x = v.x; lo.y = v.y;                                    \
          f32x2 hi; hi.x = v.z; hi.y = v.w;                                    \
          pA += lo * wih[2 * i];                                               \
          pB += hi * wih[2 * i + 1];                                           \
        }                                                                      \
        XG = (pA.x + pB.x) + (pA.y + pB.y);                                    \
      }                                                                        \
    } else if (tid >= 224) {                                                   \
      if ((t) + (OFF) + 3 < TSZ)                                               \
        *(f32x2*)(&xbuf[((OFF) + 3) & 3][2 * ll]) = XR;                        \
      if ((t) + (OFF) + 7 < TSZ)                                               \
        XR = *(const f32x2*)(xrow + (size_t)((t) + (OFF) + 7) * ISZ + 2 * ll); \
    }                                                                          \
    /* drain LDS only; loader's global loads stay in flight */                 \
    asm volatile("s_waitcnt lgkmcnt(0)" ::: "memory");                         \
    __builtin_amdgcn_s_barrier();                                              \
    __builtin_amdgcn_sched_barrier(0);                                         \
  }

__global__ __launch_bounds__(256, 2) void lstm_fused(
    const float* __restrict__ x,      // [B, T, I]
    const float* __restrict__ W_ih,   // [4H, I]
    const float* __restrict__ W_hh,   // [4H, H]
    const float* __restrict__ b_ih,   // [4H]
    const float* __restrict__ b_hh,   // [4H]
    const float* __restrict__ W_out,  // [2, H]
    const float* __restrict__ b_out,  // [2]
    float* __restrict__ out)          // [B, 2]
{
    const int row = blockIdx.x;       // one batch row per block
    const int tid = threadIdx.x;

    __shared__ __align__(16) float xbuf[4][ISZ];   // x ring (1 KiB)
    __shared__ __align__(16) float hbuf[2][56];    // h ping-pong

    // worker coords (valid tid<200)
    const int g = tid & 3;            // 0=i 1=f 2=g 3=o
    const int u = tid >> 2;           // unit
    const int k = g * HSZ + u;        // gate row in [0,200)
    const float gmul = (g == 2) ? 2.0f : 1.0f;
    const float gma  = (g == 2) ? 2.0f : 1.0f;
    const float gmb  = (g == 2) ? -1.0f : 0.0f;

    const int ll = tid - 224;         // loader lane 0..31 (tid>=224)

    const float* xrow = x + (size_t)row * (TSZ * ISZ);

    // per-lane weights
    f32x2 whh[25];
    f32x2 wih[32];
    float bias  = 0.0f;
    float c_reg = 0.0f;
    float xgE = 0.0f, xgO = 0.0f;     // xg register double-buffer (even/odd)
    f32x2 xr0{}, xr1{}, xr2{}, xr3{}; // loader in-flight regs (depth 4)

    if (tid < 200) {
        const float* wh = W_hh + k * HSZ;
        #pragma unroll
        for (int j = 0; j < 25; ++j) whh[j] = *(const f32x2*)(wh + 2 * j);
        const float* wi = W_ih + k * ISZ;
        #pragma unroll
        for (int i = 0; i < 32; ++i) wih[i] = *(const f32x2*)(wi + 2 * i);
        bias = b_ih[k] + b_hh[k];
    } else if (ll >= 0) {
        // stage x[0..2] into ring slots 0..2; preload regs with x[3..6]
        #pragma unroll
        for (int n = 0; n < 3; ++n) {
            *(f32x2*)(&xbuf[n][2 * ll]) =
                *(const f32x2*)(xrow + (size_t)n * ISZ + 2 * ll);
        }
        xr0 = *(const f32x2*)(xrow + 3 * (size_t)ISZ + 2 * ll);
        xr1 = *(const f32x2*)(xrow + 4 * (size_t)ISZ + 2 * ll);
        xr2 = *(const f32x2*)(xrow + 5 * (size_t)ISZ + 2 * ll);
        xr3 = *(const f32x2*)(xrow + 6 * (size_t)ISZ + 2 * ll);
    }
    if (tid < 56) { hbuf[0][tid] = 0.0f; hbuf[1][tid] = 0.0f; }
    __syncthreads();

    // xg prologue (registers only): even-parity from x[0], odd from x[1]
    if (tid < 200) {
        #pragma unroll
        for (int n = 0; n < 2; ++n) {
            f32x2 pA; pA.x = bias; pA.y = 0.0f;
            f32x2 pB; pB.x = 0.0f; pB.y = 0.0f;
            const float4* x4 = (const float4*)(&xbuf[n][0]);
            #pragma unroll
            for (int i = 0; i < 16; ++i) {
                float4 v = x4[i];
                f32x2 lo; lo.x = v.x; lo.y = v.y;
                f32x2 hi; hi.x = v.z; hi.y = v.w;
                pA += lo * wih[2 * i];
                pB += hi * wih[2 * i + 1];
            }
            float r = (pA.x + pB.x) + (pA.y + pB.y);
            if (n == 0) xgE = r; else xgO = r;
        }
    }

    for (int t = 0; t < TSZ; t += 4) {
        LSTM_STEP(t, 0, xr0, xgE)
        LSTM_STEP(t, 1, xr1, xgO)
        LSTM_STEP(t, 2, xr2, xgE)
        LSTM_STEP(t, 3, xr3, xgO)
    }
    // last step (s=999, OFF=3) wrote h_final into hbuf[0]; its lgkmcnt(0)
    // + s_barrier makes it visible.

    if (tid < 2) {
        float acc = b_out[tid];
        const float* wo = W_out + tid * HSZ;
        #pragma unroll
        for (int j = 0; j < HSZ; ++j) acc += hbuf[0][j] * wo[j];
        out[row * 2 + tid] = acc;
    }
}

extern "C" void kernel_launch(void* const* d_in, const int* in_sizes, int n_in,
                              void* d_out, int out_size, void* d_ws, size_t ws_size,
                              hipStream_t stream) {
    const float* x     = (const float*)d_in[0];
    const float* W_ih  = (const float*)d_in[1];
    const float* W_hh  = (const float*)d_in[2];
    const float* b_ih  = (const float*)d_in[3];
    const float* b_hh  = (const float*)d_in[4];
    const float* W_out = (const float*)d_in[5];
    const float* b_out = (const float*)d_in[6];
    float* out = (float*)d_out;

    const int B = in_sizes[0] / (TSZ * ISZ);   // 512
    hipLaunchKernelGGL(lstm_fused, dim3(B), dim3(256), 0, stream,
                       x, W_ih, W_hh, b_ih, b_hh, W_out, b_out, out);
}